// Round 4
// baseline (2624.487 us; speedup 1.0000x reference)
//
#include <hip/hip_runtime.h>
#include <stdint.h>

typedef unsigned short u16;
typedef unsigned int   u32;
typedef unsigned long long u64;
typedef __attribute__((ext_vector_type(8))) short bf16x8;
typedef __attribute__((ext_vector_type(4))) float f32x4;

#define NB   4
#define NQ   4096
#define NPT  2048
#define DIM  256
#define KNN_ 16

// ---------------- module-global scratch (no d_ws dependence) ----------------
__device__ int   g_isbf16;
__device__ int   g_knn[NB * NQ * KNN_];        // 1 MB
__device__ float g_qattn[NB * DIM];
__device__ float g_vglob[NB * DIM];
__device__ float g_attng[NB * DIM];

__device__ __forceinline__ float bf2f(u16 u) {
    union { u32 i; float f; } v; v.i = ((u32)u) << 16; return v.f;
}
__device__ __forceinline__ u16 f2bf(float f) {
    union { float f; u32 i; } v; v.f = f;
    u32 u = v.i;
    return (u16)((u + 0x7FFFu + ((u >> 16) & 1u)) >> 16);
}
// dtype-agnostic scalar load
template<int BF16>
__device__ __forceinline__ float ldf(const void* p, size_t i) {
    if (BF16) return bf2f(((const u16*)p)[i]);
    return ((const float*)p)[i];
}
// dtype-agnostic 8-element fragment load -> bf16x8 (16B-aligned in both modes)
template<int BF16>
__device__ __forceinline__ bf16x8 ldfrag(const void* p, size_t i) {
    if (BF16) return *(const bf16x8*)((const u16*)p + i);
    const float* f = (const float*)p + i;
    float4 a = *(const float4*)f;
    float4 b = *(const float4*)(f + 4);
    bf16x8 r;
    r[0] = (short)f2bf(a.x); r[1] = (short)f2bf(a.y);
    r[2] = (short)f2bf(a.z); r[3] = (short)f2bf(a.w);
    r[4] = (short)f2bf(b.x); r[5] = (short)f2bf(b.y);
    r[6] = (short)f2bf(b.z); r[7] = (short)f2bf(b.w);
    return r;
}
// XOR-swizzled element address inside a [rows][256] bf16 LDS tile
__device__ __forceinline__ int swz(int r, int c) {
    return r * DIM + ((((c >> 3) ^ (r & 7))) << 3) + (c & 7);
}

// ---------------------------------------------------------------------------
// Probe: classify input dtype from lat_rep bit patterns.
// ---------------------------------------------------------------------------
__global__ void probe_kernel(const u32* __restrict__ lat)
{
    if (threadIdx.x == 0 && blockIdx.x == 0) {
        int cnt = 0;
        for (int i = 0; i < 64; ++i) {
            u32 e = (lat[i] >> 7) & 0xFF;
            cnt += (e >= 110 && e <= 133) ? 1 : 0;
        }
        g_isbf16 = (cnt >= 32) ? 1 : 0;
    }
}

// ---------------------------------------------------------------------------
// Kernel A: exact 16-NN per query. f64 distances, index in low mantissa bits.
// ---------------------------------------------------------------------------
template<int BF16>
__global__ __launch_bounds__(256) void knn_kernel(const void* __restrict__ xyz_q,
                                                  const void* __restrict__ xyz)
{
    if (g_isbf16 != BF16) return;
    __shared__ float4 pts[NPT];                  // 32 KB
    const int b  = blockIdx.x >> 10;
    const int q0 = (blockIdx.x & 1023) << 2;
    const int t  = threadIdx.x;
    for (int i = t; i < NPT; i += 256) {
        const size_t base = ((size_t)b * NPT + i) * 3;
        pts[i] = make_float4(ldf<BF16>(xyz, base + 0),
                             ldf<BF16>(xyz, base + 1),
                             ldf<BF16>(xyz, base + 2), 0.f);
    }
    __syncthreads();

    const int w = t >> 6, lane = t & 63;
    const int q = q0 + w;
    const size_t qb = ((size_t)b * NQ + q) * 3;
    const double qx = (double)ldf<BF16>(xyz_q, qb + 0);
    const double qy = (double)ldf<BF16>(xyz_q, qb + 1);
    const double qz = (double)ldf<BF16>(xyz_q, qb + 2);

    u64 key[32];
    #pragma unroll
    for (int i = 0; i < 32; ++i) {
        const int n = (i << 6) + lane;
        float4 p = pts[n];
        double dx = qx - (double)p.x;
        double dy = qy - (double)p.y;
        double dz = qz - (double)p.z;
        double d2 = fma(dx, dx, fma(dy, dy, dz * dz));   // >= 0
        key[i] = (((u64)__double_as_longlong(d2)) & 0xFFFFFFFFFFFFF800ULL) | (u64)n;
    }
    u64 gmin[4];
    #pragma unroll
    for (int j = 0; j < 4; ++j) {
        u64 mn = key[8 * j];
        #pragma unroll
        for (int i = 1; i < 8; ++i) { u64 k2 = key[8 * j + i]; mn = k2 < mn ? k2 : mn; }
        gmin[j] = mn;
    }
    int* outp = g_knn + ((size_t)b * NQ + q) * KNN_;
    #pragma unroll 1
    for (int r = 0; r < KNN_; ++r) {
        u64 m01 = gmin[0] < gmin[1] ? gmin[0] : gmin[1];
        u64 m23 = gmin[2] < gmin[3] ? gmin[2] : gmin[3];
        u64 m   = m01 < m23 ? m01 : m23;
        #pragma unroll
        for (int off = 32; off >= 1; off >>= 1) {
            u64 o = __shfl_xor(m, off);
            m = o < m ? o : m;
        }
        if (lane == 0) outp[r] = (int)(m & 0x7FF);
        #pragma unroll
        for (int j = 0; j < 4; ++j) {
            if (gmin[j] == m) {
                u64 mn = ~0ULL;
                #pragma unroll
                for (int i = 0; i < 8; ++i) {
                    u64 k2 = key[8 * j + i];
                    k2 = (k2 == m) ? ~0ULL : k2;
                    key[8 * j + i] = k2;
                    mn = k2 < mn ? k2 : mn;
                }
                gmin[j] = mn;
            }
        }
    }
}

// ---------------------------------------------------------------------------
// Kernel B: per-batch q_attn, v_global, attn_g = MLP2(q_attn - k_global).
// ---------------------------------------------------------------------------
template<int BF16>
__global__ __launch_bounds__(256) void gtok_kernel(const void* __restrict__ lat,
    const void* __restrict__ Wq,  const void* __restrict__ Wkg, const void* __restrict__ Wvg,
    const void* __restrict__ Wg1, const void* __restrict__ bg1,
    const void* __restrict__ Wg2, const void* __restrict__ bg2)
{
    if (g_isbf16 != BF16) return;
    const int b = blockIdx.x, t = threadIdx.x;
    __shared__ float latS[DIM], xS[DIM], hS[DIM];
    latS[t] = ldf<BF16>(lat, (size_t)b * DIM + t);
    __syncthreads();
    float sq = 0.f, sk = 0.f, sv = 0.f;
    for (int i = 0; i < DIM; ++i) {
        float x = latS[i];
        sq += x * ldf<BF16>(Wq,  (size_t)t * DIM + i);
        sk += x * ldf<BF16>(Wkg, (size_t)t * DIM + i);
        sv += x * ldf<BF16>(Wvg, (size_t)t * DIM + i);
    }
    g_qattn[b * DIM + t] = sq;
    g_vglob[b * DIM + t] = sv;
    xS[t] = sq - sk;
    __syncthreads();
    float h = 0.f;
    for (int i = 0; i < DIM; ++i) h += xS[i] * ldf<BF16>(Wg1, (size_t)t * DIM + i);
    h += ldf<BF16>(bg1, t);
    hS[t] = fmaxf(h, 0.f);
    __syncthreads();
    float a = 0.f;
    for (int i = 0; i < DIM; ++i) a += hS[i] * ldf<BF16>(Wg2, (size_t)t * DIM + i);
    a += ldf<BF16>(bg2, t);
    g_attng[b * DIM + t] = a;
}

// ---------------------------------------------------------------------------
// Kernel C: fused attention. Block = 4 queries = 64 neighbor-rows, 4 waves.
// pos kept as packed bf16 pairs (32 VGPRs) -> no scratch spill.
// ---------------------------------------------------------------------------
template<int BF16>
__global__ __launch_bounds__(256, 3) void attn_kernel(
    const void* __restrict__ xyz_q, const void* __restrict__ xyz,
    const void* __restrict__ points,
    const void* __restrict__ Wd1, const void* __restrict__ bd1,
    const void* __restrict__ Wd2, const void* __restrict__ bd2,
    const void* __restrict__ Wg1, const void* __restrict__ bg1,
    const void* __restrict__ Wg2, const void* __restrict__ bg2,
    const void* __restrict__ Wk,  const void* __restrict__ Wv,
    void* __restrict__ out)
{
    if (g_isbf16 != BF16) return;
    __shared__ u16 bufA[64 * DIM];               // 32 KB swizzled activations
    __shared__ int nbrS[64];
    __shared__ float wd1S[DIM * 4];              // (w0,w1,w2,bd1) per output col
    __shared__ float qaS[DIM], agS[DIM], vgS[DIM];
    __shared__ float bd2S[DIM], bg1S[DIM], bg2S[DIM];

    const int b  = blockIdx.x >> 10;
    const int q0 = (blockIdx.x & 1023) << 2;
    const int t  = threadIdx.x;

    // ---- stage 0: small shared data
    wd1S[t * 4 + 0] = ldf<BF16>(Wd1, (size_t)t * 3 + 0);
    wd1S[t * 4 + 1] = ldf<BF16>(Wd1, (size_t)t * 3 + 1);
    wd1S[t * 4 + 2] = ldf<BF16>(Wd1, (size_t)t * 3 + 2);
    wd1S[t * 4 + 3] = ldf<BF16>(bd1, t);
    bd2S[t] = ldf<BF16>(bd2, t);
    bg1S[t] = ldf<BF16>(bg1, t);
    bg2S[t] = ldf<BF16>(bg2, t);
    qaS[t] = g_qattn[b * DIM + t];
    agS[t] = g_attng[b * DIM + t];
    vgS[t] = g_vglob[b * DIM + t];
    if (t < 64) {
        int qq = q0 + (t >> 4);
        nbrS[t] = g_knn[((size_t)b * NQ + qq) * KNN_ + (t & 15)];
    }
    __syncthreads();

    const int w = t >> 6, lane = t & 63;
    const int q  = q0 + w;                       // one query per wave
    const int rw = w << 4;                       // this wave's 16 rows
    const int q4 = lane >> 4, l15 = lane & 15;
    const int arow = rw + l15;

    // ---- issue gathered P-fragment loads early (latency hidden by stage 1)
    const size_t prow = ((size_t)b * NPT + nbrS[arow]) * DIM;
    bf16x8 afrP[8];
    #pragma unroll
    for (int kt = 0; kt < 8; ++kt)
        afrP[kt] = ldfrag<BF16>(points, prow + ((((kt << 2) + q4)) << 3));

    // ---- stage 1: h1 = relu(d @ Wd1^T + bd1) -> bufA (bf16)
    {
        const int r = rw + (lane >> 2);
        const int n = nbrS[r];
        const size_t nb3 = ((size_t)b * NPT + n) * 3;
        const size_t qb3 = ((size_t)b * NQ  + q) * 3;
        const float dx = ldf<BF16>(xyz_q, qb3 + 0) - ldf<BF16>(xyz, nb3 + 0);
        const float dy = ldf<BF16>(xyz_q, qb3 + 1) - ldf<BF16>(xyz, nb3 + 1);
        const float dz = ldf<BF16>(xyz_q, qb3 + 2) - ldf<BF16>(xyz, nb3 + 2);
        #pragma unroll
        for (int ci = 0; ci < 8; ++ci) {
            const int kc = (lane & 3) + (ci << 2);
            u32 hw[4];
            #pragma unroll
            for (int pp = 0; pp < 4; ++pp) {
                const int c = (kc << 3) + pp * 2;
                const float* wv0 = wd1S + (size_t)c * 4;
                const float* wv1 = wd1S + (size_t)(c + 1) * 4;
                float h0 = wv0[0] * dx + wv0[1] * dy + wv0[2] * dz + wv0[3];
                float h1 = wv1[0] * dx + wv1[1] * dy + wv1[2] * dz + wv1[3];
                hw[pp] = (u32)f2bf(fmaxf(h0, 0.f)) | ((u32)f2bf(fmaxf(h1, 0.f)) << 16);
            }
            *(uint4*)(bufA + r * DIM + ((kc ^ (r & 7)) << 3)) = make_uint4(hw[0], hw[1], hw[2], hw[3]);
        }
    }
    __syncthreads();

    // h1 fragments from LDS
    bf16x8 afrA[8];
    #pragma unroll
    for (int kt = 0; kt < 8; ++kt)
        afrA[kt] = *(const bf16x8*)(bufA + arow * DIM + ((((kt << 2) + q4) ^ (arow & 7)) << 3));

    // ---- stage 2: pos = h1@Wd2^T + bd2 (packed bf16 pairs in 32 VGPRs);
    //               K = P@Wk^T; attn_in = (q_attn - K) + pos -> bufA (bf16)
    u32 posp[32];
    #pragma unroll
    for (int ct = 0; ct < 16; ++ct) {
        const int colg = (ct << 4) + l15;
        f32x4 accP = {0.f, 0.f, 0.f, 0.f};
        f32x4 accK = {0.f, 0.f, 0.f, 0.f};
        #pragma unroll
        for (int kt = 0; kt < 8; ++kt) {
            bf16x8 bfrD = ldfrag<BF16>(Wd2, (size_t)colg * DIM + (kt << 5) + (q4 << 3));
            bf16x8 bfrK = ldfrag<BF16>(Wk,  (size_t)colg * DIM + (kt << 5) + (q4 << 3));
            accP = __builtin_amdgcn_mfma_f32_16x16x32_bf16(afrA[kt], bfrD, accP, 0, 0, 0);
            accK = __builtin_amdgcn_mfma_f32_16x16x32_bf16(afrP[kt], bfrK, accK, 0, 0, 0);
        }
        const float bb = bd2S[colg];
        const float qa = qaS[colg];
        u16 pb[4];
        #pragma unroll
        for (int reg = 0; reg < 4; ++reg) {
            const float pv = accP[reg] + bb;
            pb[reg] = f2bf(pv);
            const int rr = rw + (q4 << 2) + reg;
            bufA[swz(rr, colg)] = f2bf((qa - accK[reg]) + pv);
        }
        posp[(ct << 1) + 0] = (u32)pb[0] | ((u32)pb[1] << 16);
        posp[(ct << 1) + 1] = (u32)pb[2] | ((u32)pb[3] << 16);
    }
    __syncthreads();

    // ---- stage 3: g1 = relu(attn_in@Wg1^T + bg1) -> bufA (bf16)
    #pragma unroll
    for (int kt = 0; kt < 8; ++kt)
        afrA[kt] = *(const bf16x8*)(bufA + arow * DIM + ((((kt << 2) + q4) ^ (arow & 7)) << 3));
    #pragma unroll
    for (int ct = 0; ct < 16; ++ct) {
        const int colg = (ct << 4) + l15;
        f32x4 acc = {0.f, 0.f, 0.f, 0.f};
        #pragma unroll
        for (int kt = 0; kt < 8; ++kt) {
            bf16x8 bfr = ldfrag<BF16>(Wg1, (size_t)colg * DIM + (kt << 5) + (q4 << 3));
            acc = __builtin_amdgcn_mfma_f32_16x16x32_bf16(afrA[kt], bfr, acc, 0, 0, 0);
        }
        const float bb = bg1S[colg];
        #pragma unroll
        for (int reg = 0; reg < 4; ++reg) {
            const int rr = rw + (q4 << 2) + reg;
            bufA[swz(rr, colg)] = f2bf(fmaxf(acc[reg] + bb, 0.f));
        }
    }
    __syncthreads();

    // ---- stage 4: logits = g1@Wg2^T + bg2; V = P@Wv^T; softmax; output
    #pragma unroll
    for (int kt = 0; kt < 8; ++kt)
        afrA[kt] = *(const bf16x8*)(bufA + arow * DIM + ((((kt << 2) + q4) ^ (arow & 7)) << 3));
    const size_t outq = ((size_t)b * NQ + q) * DIM;
    #pragma unroll
    for (int ct = 0; ct < 16; ++ct) {
        const int colg = (ct << 4) + l15;
        f32x4 accL = {0.f, 0.f, 0.f, 0.f};
        f32x4 accV = {0.f, 0.f, 0.f, 0.f};
        #pragma unroll
        for (int kt = 0; kt < 8; ++kt) {
            bf16x8 bfrG = ldfrag<BF16>(Wg2, (size_t)colg * DIM + (kt << 5) + (q4 << 3));
            bf16x8 bfrV = ldfrag<BF16>(Wv,  (size_t)colg * DIM + (kt << 5) + (q4 << 3));
            accL = __builtin_amdgcn_mfma_f32_16x16x32_bf16(afrA[kt], bfrG, accL, 0, 0, 0);
            accV = __builtin_amdgcn_mfma_f32_16x16x32_bf16(afrP[kt], bfrV, accV, 0, 0, 0);
        }
        const float bb = bg2S[colg];
        const float l0 = fminf(30.f, fmaxf(-30.f, accL[0] + bb));
        const float l1 = fminf(30.f, fmaxf(-30.f, accL[1] + bb));
        const float l2 = fminf(30.f, fmaxf(-30.f, accL[2] + bb));
        const float l3 = fminf(30.f, fmaxf(-30.f, accL[3] + bb));
        const float gl = fminf(30.f, fmaxf(-30.f, agS[colg]));
        float mx = fmaxf(fmaxf(l0, l1), fmaxf(l2, l3));
        mx = fmaxf(mx, __shfl_xor(mx, 16));
        mx = fmaxf(mx, __shfl_xor(mx, 32));
        mx = fmaxf(mx, gl);
        const float e0 = expf(l0 - mx), e1 = expf(l1 - mx);
        const float e2 = expf(l2 - mx), e3 = expf(l3 - mx);
        float s = (e0 + e1) + (e2 + e3);
        s += __shfl_xor(s, 16);
        s += __shfl_xor(s, 32);
        const float eg  = expf(gl - mx);
        const float inv = 1.0f / (s + eg);
        const u32 p01 = posp[(ct << 1) + 0];
        const u32 p23 = posp[(ct << 1) + 1];
        float o = e0 * (accV[0] + bf2f((u16)(p01 & 0xFFFF)))
                + e1 * (accV[1] + bf2f((u16)(p01 >> 16)))
                + e2 * (accV[2] + bf2f((u16)(p23 & 0xFFFF)))
                + e3 * (accV[3] + bf2f((u16)(p23 >> 16)));
        o += __shfl_xor(o, 16);
        o += __shfl_xor(o, 32);
        o = (o + eg * vgS[colg]) * inv;
        if (lane < 16) {
            if (BF16) ((u16*)out)[outq + colg] = f2bf(o);
            else      ((float*)out)[outq + colg] = o;
        }
    }
}

// ---------------------------------------------------------------------------
extern "C" void kernel_launch(void* const* d_in, const int* in_sizes, int n_in,
                              void* d_out, int out_size, void* d_ws, size_t ws_size,
                              hipStream_t stream)
{
    const void* xyz_q  = d_in[0];
    const void* lat    = d_in[1];
    const void* xyz    = d_in[2];
    const void* points = d_in[3];
    const void* Wd1 = d_in[4];
    const void* bd1 = d_in[5];
    const void* Wd2 = d_in[6];
    const void* bd2 = d_in[7];
    const void* Wg1 = d_in[8];
    const void* bg1 = d_in[9];
    const void* Wg2 = d_in[10];
    const void* bg2 = d_in[11];
    const void* Wkg = d_in[12];
    const void* Wvg = d_in[13];
    const void* Wq  = d_in[14];
    const void* Wk  = d_in[15];
    const void* Wv  = d_in[16];

    probe_kernel<<<1, 64, 0, stream>>>((const u32*)lat);

    knn_kernel<1><<<4096, 256, 0, stream>>>(xyz_q, xyz);
    knn_kernel<0><<<4096, 256, 0, stream>>>(xyz_q, xyz);
    gtok_kernel<1><<<4, 256, 0, stream>>>(lat, Wq, Wkg, Wvg, Wg1, bg1, Wg2, bg2);
    gtok_kernel<0><<<4, 256, 0, stream>>>(lat, Wq, Wkg, Wvg, Wg1, bg1, Wg2, bg2);
    attn_kernel<1><<<4096, 256, 0, stream>>>(xyz_q, xyz, points,
                                             Wd1, bd1, Wd2, bd2, Wg1, bg1, Wg2, bg2,
                                             Wk, Wv, d_out);
    attn_kernel<0><<<4096, 256, 0, stream>>>(xyz_q, xyz, points,
                                             Wd1, bd1, Wd2, bd2, Wg1, bg1, Wg2, bg2,
                                             Wk, Wv, d_out);
}

// Round 5
// 2462.178 us; speedup vs baseline: 1.0659x; 1.0659x over previous
//
#include <hip/hip_runtime.h>
#include <stdint.h>

typedef unsigned short u16;
typedef unsigned int   u32;
typedef unsigned long long u64;
typedef __attribute__((ext_vector_type(8))) short bf16x8;
typedef __attribute__((ext_vector_type(4))) float f32x4;

#define NB   4
#define NQ   4096
#define NPT  2048
#define DIM  256
#define KNN_ 16

// ---------------- module-global scratch (no d_ws dependence) ----------------
__device__ int   g_isbf16;
__device__ int   g_knn[NB * NQ * KNN_];        // 1 MB
__device__ float g_qattn[NB * DIM];
__device__ float g_vglob[NB * DIM];
__device__ float g_attng[NB * DIM];

__device__ __forceinline__ float bf2f(u16 u) {
    union { u32 i; float f; } v; v.i = ((u32)u) << 16; return v.f;
}
__device__ __forceinline__ u16 f2bf(float f) {
    union { float f; u32 i; } v; v.f = f;
    u32 u = v.i;
    return (u16)((u + 0x7FFFu + ((u >> 16) & 1u)) >> 16);
}
// dtype-agnostic scalar load
template<int BF16>
__device__ __forceinline__ float ldf(const void* p, size_t i) {
    if (BF16) return bf2f(((const u16*)p)[i]);
    return ((const float*)p)[i];
}
// dtype-agnostic 8-element fragment load -> bf16x8 (16B-aligned in both modes)
template<int BF16>
__device__ __forceinline__ bf16x8 ldfrag(const void* p, size_t i) {
    if (BF16) return *(const bf16x8*)((const u16*)p + i);
    const float* f = (const float*)p + i;
    float4 a = *(const float4*)f;
    float4 b = *(const float4*)(f + 4);
    bf16x8 r;
    r[0] = (short)f2bf(a.x); r[1] = (short)f2bf(a.y);
    r[2] = (short)f2bf(a.z); r[3] = (short)f2bf(a.w);
    r[4] = (short)f2bf(b.x); r[5] = (short)f2bf(b.y);
    r[6] = (short)f2bf(b.z); r[7] = (short)f2bf(b.w);
    return r;
}
// XOR-swizzled element address inside a [rows][256] bf16 LDS tile
__device__ __forceinline__ int swz(int r, int c) {
    return r * DIM + ((((c >> 3) ^ (r & 7))) << 3) + (c & 7);
}

// ---------------------------------------------------------------------------
// Probe: classify input dtype from lat_rep bit patterns.
// ---------------------------------------------------------------------------
__global__ void probe_kernel(const u32* __restrict__ lat)
{
    if (threadIdx.x == 0 && blockIdx.x == 0) {
        int cnt = 0;
        for (int i = 0; i < 64; ++i) {
            u32 e = (lat[i] >> 7) & 0xFF;
            cnt += (e >= 110 && e <= 133) ? 1 : 0;
        }
        g_isbf16 = (cnt >= 32) ? 1 : 0;
    }
}

// ---------------------------------------------------------------------------
// Kernel A: exact 16-NN per query. f64 distances, index in low mantissa bits.
// ---------------------------------------------------------------------------
template<int BF16>
__global__ __launch_bounds__(256) void knn_kernel(const void* __restrict__ xyz_q,
                                                  const void* __restrict__ xyz)
{
    if (g_isbf16 != BF16) return;
    __shared__ float4 pts[NPT];                  // 32 KB
    const int b  = blockIdx.x >> 10;
    const int q0 = (blockIdx.x & 1023) << 2;
    const int t  = threadIdx.x;
    for (int i = t; i < NPT; i += 256) {
        const size_t base = ((size_t)b * NPT + i) * 3;
        pts[i] = make_float4(ldf<BF16>(xyz, base + 0),
                             ldf<BF16>(xyz, base + 1),
                             ldf<BF16>(xyz, base + 2), 0.f);
    }
    __syncthreads();

    const int w = t >> 6, lane = t & 63;
    const int q = q0 + w;
    const size_t qb = ((size_t)b * NQ + q) * 3;
    const double qx = (double)ldf<BF16>(xyz_q, qb + 0);
    const double qy = (double)ldf<BF16>(xyz_q, qb + 1);
    const double qz = (double)ldf<BF16>(xyz_q, qb + 2);

    u64 key[32];
    #pragma unroll
    for (int i = 0; i < 32; ++i) {
        const int n = (i << 6) + lane;
        float4 p = pts[n];
        double dx = qx - (double)p.x;
        double dy = qy - (double)p.y;
        double dz = qz - (double)p.z;
        double d2 = fma(dx, dx, fma(dy, dy, dz * dz));   // >= 0
        key[i] = (((u64)__double_as_longlong(d2)) & 0xFFFFFFFFFFFFF800ULL) | (u64)n;
    }
    u64 gmin[4];
    #pragma unroll
    for (int j = 0; j < 4; ++j) {
        u64 mn = key[8 * j];
        #pragma unroll
        for (int i = 1; i < 8; ++i) { u64 k2 = key[8 * j + i]; mn = k2 < mn ? k2 : mn; }
        gmin[j] = mn;
    }
    int* outp = g_knn + ((size_t)b * NQ + q) * KNN_;
    #pragma unroll 1
    for (int r = 0; r < KNN_; ++r) {
        u64 m01 = gmin[0] < gmin[1] ? gmin[0] : gmin[1];
        u64 m23 = gmin[2] < gmin[3] ? gmin[2] : gmin[3];
        u64 m   = m01 < m23 ? m01 : m23;
        #pragma unroll
        for (int off = 32; off >= 1; off >>= 1) {
            u64 o = __shfl_xor(m, off);
            m = o < m ? o : m;
        }
        if (lane == 0) outp[r] = (int)(m & 0x7FF);
        #pragma unroll
        for (int j = 0; j < 4; ++j) {
            if (gmin[j] == m) {
                u64 mn = ~0ULL;
                #pragma unroll
                for (int i = 0; i < 8; ++i) {
                    u64 k2 = key[8 * j + i];
                    k2 = (k2 == m) ? ~0ULL : k2;
                    key[8 * j + i] = k2;
                    mn = k2 < mn ? k2 : mn;
                }
                gmin[j] = mn;
            }
        }
    }
}

// ---------------------------------------------------------------------------
// Kernel B: per-batch q_attn, v_global, attn_g = MLP2(q_attn - k_global).
// ---------------------------------------------------------------------------
template<int BF16>
__global__ __launch_bounds__(256) void gtok_kernel(const void* __restrict__ lat,
    const void* __restrict__ Wq,  const void* __restrict__ Wkg, const void* __restrict__ Wvg,
    const void* __restrict__ Wg1, const void* __restrict__ bg1,
    const void* __restrict__ Wg2, const void* __restrict__ bg2)
{
    if (g_isbf16 != BF16) return;
    const int b = blockIdx.x, t = threadIdx.x;
    __shared__ float latS[DIM], xS[DIM], hS[DIM];
    latS[t] = ldf<BF16>(lat, (size_t)b * DIM + t);
    __syncthreads();
    float sq = 0.f, sk = 0.f, sv = 0.f;
    for (int i = 0; i < DIM; ++i) {
        float x = latS[i];
        sq += x * ldf<BF16>(Wq,  (size_t)t * DIM + i);
        sk += x * ldf<BF16>(Wkg, (size_t)t * DIM + i);
        sv += x * ldf<BF16>(Wvg, (size_t)t * DIM + i);
    }
    g_qattn[b * DIM + t] = sq;
    g_vglob[b * DIM + t] = sv;
    xS[t] = sq - sk;
    __syncthreads();
    float h = 0.f;
    for (int i = 0; i < DIM; ++i) h += xS[i] * ldf<BF16>(Wg1, (size_t)t * DIM + i);
    h += ldf<BF16>(bg1, t);
    hS[t] = fmaxf(h, 0.f);
    __syncthreads();
    float a = 0.f;
    for (int i = 0; i < DIM; ++i) a += hS[i] * ldf<BF16>(Wg2, (size_t)t * DIM + i);
    a += ldf<BF16>(bg2, t);
    g_attng[b * DIM + t] = a;
}

// ---------------------------------------------------------------------------
// Kernel C: fused attention. Block = 4 queries = 64 neighbor-rows, 4 waves
// (1 query/wave). All bufA/bufVP rows are WAVE-PRIVATE -> single barrier.
// V fused into stage 2; vp = bf16(V+pos) lives in LDS (no register arrays
// except afrA) -> no scratch spill possible.
// ---------------------------------------------------------------------------
template<int BF16>
__global__ __launch_bounds__(256) void attn_kernel(
    const void* __restrict__ xyz_q, const void* __restrict__ xyz,
    const void* __restrict__ points,
    const void* __restrict__ Wd1, const void* __restrict__ bd1,
    const void* __restrict__ Wd2, const void* __restrict__ bd2,
    const void* __restrict__ Wg1, const void* __restrict__ bg1,
    const void* __restrict__ Wg2, const void* __restrict__ bg2,
    const void* __restrict__ Wk,  const void* __restrict__ Wv,
    void* __restrict__ out)
{
    if (g_isbf16 != BF16) return;
    __shared__ u16 bufA[64 * DIM];               // 32 KB swizzled activations
    __shared__ u16 bufVP[64 * DIM];              // 32 KB vp = bf16(V+pos)
    __shared__ int nbrS[64];
    __shared__ float wd1S[DIM * 4];              // (w0,w1,w2,bd1) per output col
    __shared__ float qaS[DIM], agS[DIM], vgS[DIM];
    __shared__ float bd2S[DIM], bg1S[DIM], bg2S[DIM];

    const int b  = blockIdx.x >> 10;
    const int q0 = (blockIdx.x & 1023) << 2;
    const int t  = threadIdx.x;

    // ---- stage 0: small shared data (the ONLY barrier-protected stage)
    wd1S[t * 4 + 0] = ldf<BF16>(Wd1, (size_t)t * 3 + 0);
    wd1S[t * 4 + 1] = ldf<BF16>(Wd1, (size_t)t * 3 + 1);
    wd1S[t * 4 + 2] = ldf<BF16>(Wd1, (size_t)t * 3 + 2);
    wd1S[t * 4 + 3] = ldf<BF16>(bd1, t);
    bd2S[t] = ldf<BF16>(bd2, t);
    bg1S[t] = ldf<BF16>(bg1, t);
    bg2S[t] = ldf<BF16>(bg2, t);
    qaS[t] = g_qattn[b * DIM + t];
    agS[t] = g_attng[b * DIM + t];
    vgS[t] = g_vglob[b * DIM + t];
    if (t < 64) {
        int qq = q0 + (t >> 4);
        nbrS[t] = g_knn[((size_t)b * NQ + qq) * KNN_ + (t & 15)];
    }
    __syncthreads();

    const int w = t >> 6, lane = t & 63;
    const int q  = q0 + w;                       // one query per wave
    const int rw = w << 4;                       // this wave's 16 rows
    const int q4 = lane >> 4, l15 = lane & 15;
    const int arow = rw + l15;

    // ---- issue gathered P-fragment loads early (latency hidden by stage 1)
    const size_t prow = ((size_t)b * NPT + nbrS[arow]) * DIM;
    bf16x8 afrP[8];
    #pragma unroll
    for (int kt = 0; kt < 8; ++kt)
        afrP[kt] = ldfrag<BF16>(points, prow + ((((kt << 2) + q4)) << 3));

    // ---- stage 1: h1 = relu(d @ Wd1^T + bd1) -> bufA (bf16), wave-private rows
    {
        const int r = rw + (lane >> 2);
        const int n = nbrS[r];
        const size_t nb3 = ((size_t)b * NPT + n) * 3;
        const size_t qb3 = ((size_t)b * NQ  + q) * 3;
        const float dx = ldf<BF16>(xyz_q, qb3 + 0) - ldf<BF16>(xyz, nb3 + 0);
        const float dy = ldf<BF16>(xyz_q, qb3 + 1) - ldf<BF16>(xyz, nb3 + 1);
        const float dz = ldf<BF16>(xyz_q, qb3 + 2) - ldf<BF16>(xyz, nb3 + 2);
        #pragma unroll
        for (int ci = 0; ci < 8; ++ci) {
            const int kc = (lane & 3) + (ci << 2);
            u32 hw[4];
            #pragma unroll
            for (int pp = 0; pp < 4; ++pp) {
                const int c = (kc << 3) + pp * 2;
                const float* wv0 = wd1S + (size_t)c * 4;
                const float* wv1 = wd1S + (size_t)(c + 1) * 4;
                float h0 = wv0[0] * dx + wv0[1] * dy + wv0[2] * dz + wv0[3];
                float h1 = wv1[0] * dx + wv1[1] * dy + wv1[2] * dz + wv1[3];
                hw[pp] = (u32)f2bf(fmaxf(h0, 0.f)) | ((u32)f2bf(fmaxf(h1, 0.f)) << 16);
            }
            *(uint4*)(bufA + r * DIM + ((kc ^ (r & 7)) << 3)) = make_uint4(hw[0], hw[1], hw[2], hw[3]);
        }
    }
    // no barrier: rows are wave-private; in-wave LDS RAW handled by waitcnt

    // h1 fragments from LDS
    bf16x8 afrA[8];
    #pragma unroll
    for (int kt = 0; kt < 8; ++kt)
        afrA[kt] = *(const bf16x8*)(bufA + arow * DIM + ((((kt << 2) + q4) ^ (arow & 7)) << 3));

    // ---- stage 2: pos = h1@Wd2^T + bd2; K = P@Wk^T; V = P@Wv^T.
    //      attn_in = (qa - K) + pos -> bufA;  vp = bf16(V + pos) -> bufVP.
    #pragma unroll 1
    for (int ct = 0; ct < 16; ++ct) {
        const int colg = (ct << 4) + l15;
        f32x4 accP = {0.f, 0.f, 0.f, 0.f};
        f32x4 accK = {0.f, 0.f, 0.f, 0.f};
        f32x4 accV = {0.f, 0.f, 0.f, 0.f};
        #pragma unroll
        for (int kt = 0; kt < 8; ++kt) {
            const size_t off = (size_t)colg * DIM + (kt << 5) + (q4 << 3);
            bf16x8 bfrD = ldfrag<BF16>(Wd2, off);
            bf16x8 bfrK = ldfrag<BF16>(Wk,  off);
            bf16x8 bfrV = ldfrag<BF16>(Wv,  off);
            accP = __builtin_amdgcn_mfma_f32_16x16x32_bf16(afrA[kt], bfrD, accP, 0, 0, 0);
            accK = __builtin_amdgcn_mfma_f32_16x16x32_bf16(afrP[kt], bfrK, accK, 0, 0, 0);
            accV = __builtin_amdgcn_mfma_f32_16x16x32_bf16(afrP[kt], bfrV, accV, 0, 0, 0);
        }
        const float bb = bd2S[colg];
        const float qa = qaS[colg];
        #pragma unroll
        for (int reg = 0; reg < 4; ++reg) {
            const float pv = accP[reg] + bb;
            const int rr = rw + (q4 << 2) + reg;
            bufA[swz(rr, colg)]  = f2bf((qa - accK[reg]) + pv);
            bufVP[swz(rr, colg)] = f2bf(accV[reg] + pv);
        }
    }

    // ---- stage 3: g1 = relu(attn_in@Wg1^T + bg1) -> bufA (bf16)
    #pragma unroll
    for (int kt = 0; kt < 8; ++kt)
        afrA[kt] = *(const bf16x8*)(bufA + arow * DIM + ((((kt << 2) + q4) ^ (arow & 7)) << 3));
    #pragma unroll 1
    for (int ct = 0; ct < 16; ++ct) {
        const int colg = (ct << 4) + l15;
        f32x4 acc = {0.f, 0.f, 0.f, 0.f};
        #pragma unroll
        for (int kt = 0; kt < 8; ++kt) {
            bf16x8 bfr = ldfrag<BF16>(Wg1, (size_t)colg * DIM + (kt << 5) + (q4 << 3));
            acc = __builtin_amdgcn_mfma_f32_16x16x32_bf16(afrA[kt], bfr, acc, 0, 0, 0);
        }
        const float bb = bg1S[colg];
        #pragma unroll
        for (int reg = 0; reg < 4; ++reg) {
            const int rr = rw + (q4 << 2) + reg;
            bufA[swz(rr, colg)] = f2bf(fmaxf(acc[reg] + bb, 0.f));
        }
    }

    // ---- stage 4: logits = g1@Wg2^T + bg2; softmax over 16 nbrs + global;
    //               out = sum_j w_j * vp_j + w_g * v_global
    #pragma unroll
    for (int kt = 0; kt < 8; ++kt)
        afrA[kt] = *(const bf16x8*)(bufA + arow * DIM + ((((kt << 2) + q4) ^ (arow & 7)) << 3));
    const size_t outq = ((size_t)b * NQ + q) * DIM;
    #pragma unroll 1
    for (int ct = 0; ct < 16; ++ct) {
        const int colg = (ct << 4) + l15;
        f32x4 accL = {0.f, 0.f, 0.f, 0.f};
        #pragma unroll
        for (int kt = 0; kt < 8; ++kt) {
            bf16x8 bfrG = ldfrag<BF16>(Wg2, (size_t)colg * DIM + (kt << 5) + (q4 << 3));
            accL = __builtin_amdgcn_mfma_f32_16x16x32_bf16(afrA[kt], bfrG, accL, 0, 0, 0);
        }
        const float bb = bg2S[colg];
        const float l0 = fminf(30.f, fmaxf(-30.f, accL[0] + bb));
        const float l1 = fminf(30.f, fmaxf(-30.f, accL[1] + bb));
        const float l2 = fminf(30.f, fmaxf(-30.f, accL[2] + bb));
        const float l3 = fminf(30.f, fmaxf(-30.f, accL[3] + bb));
        const float gl = fminf(30.f, fmaxf(-30.f, agS[colg]));
        float mx = fmaxf(fmaxf(l0, l1), fmaxf(l2, l3));
        mx = fmaxf(mx, __shfl_xor(mx, 16));
        mx = fmaxf(mx, __shfl_xor(mx, 32));
        mx = fmaxf(mx, gl);
        const float e0 = expf(l0 - mx), e1 = expf(l1 - mx);
        const float e2 = expf(l2 - mx), e3 = expf(l3 - mx);
        float s = (e0 + e1) + (e2 + e3);
        s += __shfl_xor(s, 16);
        s += __shfl_xor(s, 32);
        const float eg  = expf(gl - mx);
        const float inv = 1.0f / (s + eg);
        const int rr = rw + (q4 << 2);
        float o = e0 * bf2f(bufVP[swz(rr + 0, colg)])
                + e1 * bf2f(bufVP[swz(rr + 1, colg)])
                + e2 * bf2f(bufVP[swz(rr + 2, colg)])
                + e3 * bf2f(bufVP[swz(rr + 3, colg)]);
        o += __shfl_xor(o, 16);
        o += __shfl_xor(o, 32);
        o = (o + eg * vgS[colg]) * inv;
        if (lane < 16) {
            if (BF16) ((u16*)out)[outq + colg] = f2bf(o);
            else      ((float*)out)[outq + colg] = o;
        }
    }
}

// ---------------------------------------------------------------------------
extern "C" void kernel_launch(void* const* d_in, const int* in_sizes, int n_in,
                              void* d_out, int out_size, void* d_ws, size_t ws_size,
                              hipStream_t stream)
{
    const void* xyz_q  = d_in[0];
    const void* lat    = d_in[1];
    const void* xyz    = d_in[2];
    const void* points = d_in[3];
    const void* Wd1 = d_in[4];
    const void* bd1 = d_in[5];
    const void* Wd2 = d_in[6];
    const void* bd2 = d_in[7];
    const void* Wg1 = d_in[8];
    const void* bg1 = d_in[9];
    const void* Wg2 = d_in[10];
    const void* bg2 = d_in[11];
    const void* Wkg = d_in[12];
    const void* Wvg = d_in[13];
    const void* Wq  = d_in[14];
    const void* Wk  = d_in[15];
    const void* Wv  = d_in[16];

    probe_kernel<<<1, 64, 0, stream>>>((const u32*)lat);

    knn_kernel<1><<<4096, 256, 0, stream>>>(xyz_q, xyz);
    knn_kernel<0><<<4096, 256, 0, stream>>>(xyz_q, xyz);
    gtok_kernel<1><<<4, 256, 0, stream>>>(lat, Wq, Wkg, Wvg, Wg1, bg1, Wg2, bg2);
    gtok_kernel<0><<<4, 256, 0, stream>>>(lat, Wq, Wkg, Wvg, Wg1, bg1, Wg2, bg2);
    attn_kernel<1><<<4096, 256, 0, stream>>>(xyz_q, xyz, points,
                                             Wd1, bd1, Wd2, bd2, Wg1, bg1, Wg2, bg2,
                                             Wk, Wv, d_out);
    attn_kernel<0><<<4096, 256, 0, stream>>>(xyz_q, xyz, points,
                                             Wd1, bd1, Wd2, bd2, Wg1, bg1, Wg2, bg2,
                                             Wk, Wv, d_out);
}

// Round 6
// 602.511 us; speedup vs baseline: 4.3559x; 4.0865x over previous
//
#include <hip/hip_runtime.h>
#include <stdint.h>

typedef unsigned short u16;
typedef unsigned int   u32;
typedef unsigned long long u64;
typedef __attribute__((ext_vector_type(8))) short bf16x8;
typedef __attribute__((ext_vector_type(4))) float f32x4;

#define NB   4
#define NQ   4096
#define NPT  2048
#define DIM  256
#define KNN_ 16

// ---------------- module-global scratch (no d_ws dependence) ----------------
__device__ int   g_isbf16;
__device__ int   g_knn[NB * NQ * KNN_];        // 1 MB
__device__ float g_qattn[NB * DIM];
__device__ float g_vglob[NB * DIM];
__device__ float g_attng[NB * DIM];
// fragment-ordered packed weights: [mat][ct][kt][lane][8] ; mats: Wd2,Wk,Wv,Wg1,Wg2
__device__ u16   g_wpack[5 * DIM * DIM];       // 640 KB

__device__ __forceinline__ float bf2f(u16 u) {
    union { u32 i; float f; } v; v.i = ((u32)u) << 16; return v.f;
}
__device__ __forceinline__ u16 f2bf(float f) {
    union { float f; u32 i; } v; v.f = f;
    u32 u = v.i;
    return (u16)((u + 0x7FFFu + ((u >> 16) & 1u)) >> 16);
}
// dtype-agnostic scalar load
template<int BF16>
__device__ __forceinline__ float ldf(const void* p, size_t i) {
    if (BF16) return bf2f(((const u16*)p)[i]);
    return ((const float*)p)[i];
}
// dtype-agnostic 8-element fragment load -> bf16x8 (16B-aligned in both modes)
template<int BF16>
__device__ __forceinline__ bf16x8 ldfrag(const void* p, size_t i) {
    if (BF16) return *(const bf16x8*)((const u16*)p + i);
    const float* f = (const float*)p + i;
    float4 a = *(const float4*)f;
    float4 b = *(const float4*)(f + 4);
    bf16x8 r;
    r[0] = (short)f2bf(a.x); r[1] = (short)f2bf(a.y);
    r[2] = (short)f2bf(a.z); r[3] = (short)f2bf(a.w);
    r[4] = (short)f2bf(b.x); r[5] = (short)f2bf(b.y);
    r[6] = (short)f2bf(b.z); r[7] = (short)f2bf(b.w);
    return r;
}
// XOR-swizzled element address inside a [rows][256] bf16 LDS tile
__device__ __forceinline__ int swz(int r, int c) {
    return r * DIM + ((((c >> 3) ^ (r & 7))) << 3) + (c & 7);
}

// ---------------------------------------------------------------------------
// Probe: classify input dtype from lat_rep bit patterns.
// ---------------------------------------------------------------------------
__global__ void probe_kernel(const u32* __restrict__ lat)
{
    if (threadIdx.x == 0 && blockIdx.x == 0) {
        int cnt = 0;
        for (int i = 0; i < 64; ++i) {
            u32 e = (lat[i] >> 7) & 0xFF;
            cnt += (e >= 110 && e <= 133) ? 1 : 0;
        }
        g_isbf16 = (cnt >= 32) ? 1 : 0;
    }
}

// ---------------------------------------------------------------------------
// Repack the 5 hot weight matrices into MFMA-fragment order:
// dst[(((ct*8+kt)*4+q4)*16+l15)*8 + j] = W[ct*16+l15][kt*32+q4*8+j]
// so a wave's B-fragment load for (ct,kt) is base + lane*16B (contiguous 1KB).
// ---------------------------------------------------------------------------
template<int BF16>
__global__ __launch_bounds__(256) void repack_kernel(
    const void* __restrict__ Wd2, const void* __restrict__ Wk,
    const void* __restrict__ Wv,  const void* __restrict__ Wg1,
    const void* __restrict__ Wg2)
{
    if (g_isbf16 != BF16) return;
    const void* srcs[5] = { Wd2, Wk, Wv, Wg1, Wg2 };
    const int m   = blockIdx.y;
    const int tid = blockIdx.x * 256 + threadIdx.x;   // 0..8191
    const int ct  = tid >> 9;
    const int kt  = (tid >> 6) & 7;
    const int q4  = (tid >> 4) & 3;
    const int l15 = tid & 15;
    const int row = ct * 16 + l15;
    const int col = (kt << 5) + (q4 << 3);
    bf16x8 v = ldfrag<BF16>(srcs[m], (size_t)row * DIM + col);
    *(bf16x8*)(g_wpack + m * DIM * DIM + (tid << 3)) = v;
}

// ---------------------------------------------------------------------------
// Kernel A: exact 16-NN per query. f64 distances, index in low mantissa bits.
// ---------------------------------------------------------------------------
template<int BF16>
__global__ __launch_bounds__(256) void knn_kernel(const void* __restrict__ xyz_q,
                                                  const void* __restrict__ xyz)
{
    if (g_isbf16 != BF16) return;
    __shared__ float4 pts[NPT];                  // 32 KB
    const int b  = blockIdx.x >> 10;
    const int q0 = (blockIdx.x & 1023) << 2;
    const int t  = threadIdx.x;
    for (int i = t; i < NPT; i += 256) {
        const size_t base = ((size_t)b * NPT + i) * 3;
        pts[i] = make_float4(ldf<BF16>(xyz, base + 0),
                             ldf<BF16>(xyz, base + 1),
                             ldf<BF16>(xyz, base + 2), 0.f);
    }
    __syncthreads();

    const int w = t >> 6, lane = t & 63;
    const int q = q0 + w;
    const size_t qb = ((size_t)b * NQ + q) * 3;
    const double qx = (double)ldf<BF16>(xyz_q, qb + 0);
    const double qy = (double)ldf<BF16>(xyz_q, qb + 1);
    const double qz = (double)ldf<BF16>(xyz_q, qb + 2);

    u64 key[32];
    #pragma unroll
    for (int i = 0; i < 32; ++i) {
        const int n = (i << 6) + lane;
        float4 p = pts[n];
        double dx = qx - (double)p.x;
        double dy = qy - (double)p.y;
        double dz = qz - (double)p.z;
        double d2 = fma(dx, dx, fma(dy, dy, dz * dz));   // >= 0
        key[i] = (((u64)__double_as_longlong(d2)) & 0xFFFFFFFFFFFFF800ULL) | (u64)n;
    }
    u64 gmin[4];
    #pragma unroll
    for (int j = 0; j < 4; ++j) {
        u64 mn = key[8 * j];
        #pragma unroll
        for (int i = 1; i < 8; ++i) { u64 k2 = key[8 * j + i]; mn = k2 < mn ? k2 : mn; }
        gmin[j] = mn;
    }
    int* outp = g_knn + ((size_t)b * NQ + q) * KNN_;
    #pragma unroll 1
    for (int r = 0; r < KNN_; ++r) {
        u64 m01 = gmin[0] < gmin[1] ? gmin[0] : gmin[1];
        u64 m23 = gmin[2] < gmin[3] ? gmin[2] : gmin[3];
        u64 m   = m01 < m23 ? m01 : m23;
        #pragma unroll
        for (int off = 32; off >= 1; off >>= 1) {
            u64 o = __shfl_xor(m, off);
            m = o < m ? o : m;
        }
        if (lane == 0) outp[r] = (int)(m & 0x7FF);
        #pragma unroll
        for (int j = 0; j < 4; ++j) {
            if (gmin[j] == m) {
                u64 mn = ~0ULL;
                #pragma unroll
                for (int i = 0; i < 8; ++i) {
                    u64 k2 = key[8 * j + i];
                    k2 = (k2 == m) ? ~0ULL : k2;
                    key[8 * j + i] = k2;
                    mn = k2 < mn ? k2 : mn;
                }
                gmin[j] = mn;
            }
        }
    }
}

// ---------------------------------------------------------------------------
// Kernel B: per-batch q_attn, v_global, attn_g = MLP2(q_attn - k_global).
// ---------------------------------------------------------------------------
template<int BF16>
__global__ __launch_bounds__(256) void gtok_kernel(const void* __restrict__ lat,
    const void* __restrict__ Wq,  const void* __restrict__ Wkg, const void* __restrict__ Wvg,
    const void* __restrict__ Wg1, const void* __restrict__ bg1,
    const void* __restrict__ Wg2, const void* __restrict__ bg2)
{
    if (g_isbf16 != BF16) return;
    const int b = blockIdx.x, t = threadIdx.x;
    __shared__ float latS[DIM], xS[DIM], hS[DIM];
    latS[t] = ldf<BF16>(lat, (size_t)b * DIM + t);
    __syncthreads();
    float sq = 0.f, sk = 0.f, sv = 0.f;
    for (int i = 0; i < DIM; ++i) {
        float x = latS[i];
        sq += x * ldf<BF16>(Wq,  (size_t)t * DIM + i);
        sk += x * ldf<BF16>(Wkg, (size_t)t * DIM + i);
        sv += x * ldf<BF16>(Wvg, (size_t)t * DIM + i);
    }
    g_qattn[b * DIM + t] = sq;
    g_vglob[b * DIM + t] = sv;
    xS[t] = sq - sk;
    __syncthreads();
    float h = 0.f;
    for (int i = 0; i < DIM; ++i) h += xS[i] * ldf<BF16>(Wg1, (size_t)t * DIM + i);
    h += ldf<BF16>(bg1, t);
    hS[t] = fmaxf(h, 0.f);
    __syncthreads();
    float a = 0.f;
    for (int i = 0; i < DIM; ++i) a += hS[i] * ldf<BF16>(Wg2, (size_t)t * DIM + i);
    a += ldf<BF16>(bg2, t);
    g_attng[b * DIM + t] = a;
}

// ---------------------------------------------------------------------------
// Kernel C: fused attention. Block = 4 queries = 64 neighbor-rows, 4 waves
// (1 query/wave). Weight B-fragments come from g_wpack (contiguous per-wave
// 1KB loads). bufA/bufVP rows are wave-private -> single barrier.
// ---------------------------------------------------------------------------
template<int BF16>
__global__ __launch_bounds__(256) void attn_kernel(
    const void* __restrict__ xyz_q, const void* __restrict__ xyz,
    const void* __restrict__ points,
    const void* __restrict__ Wd1, const void* __restrict__ bd1,
    const void* __restrict__ bd2, const void* __restrict__ bg1,
    const void* __restrict__ bg2,
    void* __restrict__ out)
{
    if (g_isbf16 != BF16) return;
    __shared__ u16 bufA[64 * DIM];               // 32 KB swizzled activations
    __shared__ u16 bufVP[64 * DIM];              // 32 KB vp = bf16(V+pos)
    __shared__ int nbrS[64];
    __shared__ float wd1S[DIM * 4];              // (w0,w1,w2,bd1) per output col
    __shared__ float qaS[DIM], agS[DIM], vgS[DIM];
    __shared__ float bd2S[DIM], bg1S[DIM], bg2S[DIM];

    const int b  = blockIdx.x >> 10;
    const int q0 = (blockIdx.x & 1023) << 2;
    const int t  = threadIdx.x;

    // ---- stage 0: small shared data (the ONLY barrier-protected stage)
    wd1S[t * 4 + 0] = ldf<BF16>(Wd1, (size_t)t * 3 + 0);
    wd1S[t * 4 + 1] = ldf<BF16>(Wd1, (size_t)t * 3 + 1);
    wd1S[t * 4 + 2] = ldf<BF16>(Wd1, (size_t)t * 3 + 2);
    wd1S[t * 4 + 3] = ldf<BF16>(bd1, t);
    bd2S[t] = ldf<BF16>(bd2, t);
    bg1S[t] = ldf<BF16>(bg1, t);
    bg2S[t] = ldf<BF16>(bg2, t);
    qaS[t] = g_qattn[b * DIM + t];
    agS[t] = g_attng[b * DIM + t];
    vgS[t] = g_vglob[b * DIM + t];
    if (t < 64) {
        int qq = q0 + (t >> 4);
        nbrS[t] = g_knn[((size_t)b * NQ + qq) * KNN_ + (t & 15)];
    }
    __syncthreads();

    const int w = t >> 6, lane = t & 63;
    const int q  = q0 + w;                       // one query per wave
    const int rw = w << 4;                       // this wave's 16 rows
    const int q4 = lane >> 4, l15 = lane & 15;
    const int arow = rw + l15;

    // packed-weight bases (fragment order): frag index = (ct*8+kt)*64 + lane
    const u16* WpD2 = g_wpack + 0 * DIM * DIM;
    const u16* WpK  = g_wpack + 1 * DIM * DIM;
    const u16* WpV  = g_wpack + 2 * DIM * DIM;
    const u16* WpG1 = g_wpack + 3 * DIM * DIM;
    const u16* WpG2 = g_wpack + 4 * DIM * DIM;

    // ---- issue gathered P-fragment loads early (latency hidden by stage 1)
    const size_t prow = ((size_t)b * NPT + nbrS[arow]) * DIM;
    bf16x8 afrP[8];
    #pragma unroll
    for (int kt = 0; kt < 8; ++kt)
        afrP[kt] = ldfrag<BF16>(points, prow + ((((kt << 2) + q4)) << 3));

    // ---- stage 1: h1 = relu(d @ Wd1^T + bd1) -> bufA (bf16), wave-private rows
    {
        const int r = rw + (lane >> 2);
        const int n = nbrS[r];
        const size_t nb3 = ((size_t)b * NPT + n) * 3;
        const size_t qb3 = ((size_t)b * NQ  + q) * 3;
        const float dx = ldf<BF16>(xyz_q, qb3 + 0) - ldf<BF16>(xyz, nb3 + 0);
        const float dy = ldf<BF16>(xyz_q, qb3 + 1) - ldf<BF16>(xyz, nb3 + 1);
        const float dz = ldf<BF16>(xyz_q, qb3 + 2) - ldf<BF16>(xyz, nb3 + 2);
        #pragma unroll
        for (int ci = 0; ci < 8; ++ci) {
            const int kc = (lane & 3) + (ci << 2);
            u32 hw[4];
            #pragma unroll
            for (int pp = 0; pp < 4; ++pp) {
                const int c = (kc << 3) + pp * 2;
                const float* wv0 = wd1S + (size_t)c * 4;
                const float* wv1 = wd1S + (size_t)(c + 1) * 4;
                float h0 = wv0[0] * dx + wv0[1] * dy + wv0[2] * dz + wv0[3];
                float h1 = wv1[0] * dx + wv1[1] * dy + wv1[2] * dz + wv1[3];
                hw[pp] = (u32)f2bf(fmaxf(h0, 0.f)) | ((u32)f2bf(fmaxf(h1, 0.f)) << 16);
            }
            *(uint4*)(bufA + r * DIM + ((kc ^ (r & 7)) << 3)) = make_uint4(hw[0], hw[1], hw[2], hw[3]);
        }
    }
    // no barrier: rows are wave-private; in-wave LDS RAW handled by waitcnt

    // h1 fragments from LDS
    bf16x8 afrA[8];
    #pragma unroll
    for (int kt = 0; kt < 8; ++kt)
        afrA[kt] = *(const bf16x8*)(bufA + arow * DIM + ((((kt << 2) + q4) ^ (arow & 7)) << 3));

    // ---- stage 2: pos = h1@Wd2^T + bd2; K = P@Wk^T; V = P@Wv^T.
    //      attn_in = (qa - K) + pos -> bufA;  vp = bf16(V + pos) -> bufVP.
    #pragma unroll 1
    for (int ct = 0; ct < 16; ++ct) {
        const int colg = (ct << 4) + l15;
        const int fbase = ((ct << 3) * 64 + lane) << 3;   // + kt*64*8 per kt
        f32x4 accP = {0.f, 0.f, 0.f, 0.f};
        f32x4 accK = {0.f, 0.f, 0.f, 0.f};
        f32x4 accV = {0.f, 0.f, 0.f, 0.f};
        #pragma unroll
        for (int kt = 0; kt < 8; ++kt) {
            const int fo = fbase + (kt << 9);
            bf16x8 bfrD = *(const bf16x8*)(WpD2 + fo);
            bf16x8 bfrK = *(const bf16x8*)(WpK  + fo);
            bf16x8 bfrV = *(const bf16x8*)(WpV  + fo);
            accP = __builtin_amdgcn_mfma_f32_16x16x32_bf16(afrA[kt], bfrD, accP, 0, 0, 0);
            accK = __builtin_amdgcn_mfma_f32_16x16x32_bf16(afrP[kt], bfrK, accK, 0, 0, 0);
            accV = __builtin_amdgcn_mfma_f32_16x16x32_bf16(afrP[kt], bfrV, accV, 0, 0, 0);
        }
        const float bb = bd2S[colg];
        const float qa = qaS[colg];
        #pragma unroll
        for (int reg = 0; reg < 4; ++reg) {
            const float pv = accP[reg] + bb;
            const int rr = rw + (q4 << 2) + reg;
            bufA[swz(rr, colg)]  = f2bf((qa - accK[reg]) + pv);
            bufVP[swz(rr, colg)] = f2bf(accV[reg] + pv);
        }
    }

    // ---- stage 3: g1 = relu(attn_in@Wg1^T + bg1) -> bufA (bf16)
    #pragma unroll
    for (int kt = 0; kt < 8; ++kt)
        afrA[kt] = *(const bf16x8*)(bufA + arow * DIM + ((((kt << 2) + q4) ^ (arow & 7)) << 3));
    #pragma unroll 1
    for (int ct = 0; ct < 16; ++ct) {
        const int colg = (ct << 4) + l15;
        const int fbase = ((ct << 3) * 64 + lane) << 3;
        f32x4 acc = {0.f, 0.f, 0.f, 0.f};
        #pragma unroll
        for (int kt = 0; kt < 8; ++kt) {
            bf16x8 bfr = *(const bf16x8*)(WpG1 + fbase + (kt << 9));
            acc = __builtin_amdgcn_mfma_f32_16x16x32_bf16(afrA[kt], bfr, acc, 0, 0, 0);
        }
        const float bb = bg1S[colg];
        #pragma unroll
        for (int reg = 0; reg < 4; ++reg) {
            const int rr = rw + (q4 << 2) + reg;
            bufA[swz(rr, colg)] = f2bf(fmaxf(acc[reg] + bb, 0.f));
        }
    }

    // ---- stage 4: logits = g1@Wg2^T + bg2; softmax over 16 nbrs + global;
    //               out = sum_j w_j * vp_j + w_g * v_global
    #pragma unroll
    for (int kt = 0; kt < 8; ++kt)
        afrA[kt] = *(const bf16x8*)(bufA + arow * DIM + ((((kt << 2) + q4) ^ (arow & 7)) << 3));
    const size_t outq = ((size_t)b * NQ + q) * DIM;
    #pragma unroll 1
    for (int ct = 0; ct < 16; ++ct) {
        const int colg = (ct << 4) + l15;
        const int fbase = ((ct << 3) * 64 + lane) << 3;
        f32x4 accL = {0.f, 0.f, 0.f, 0.f};
        #pragma unroll
        for (int kt = 0; kt < 8; ++kt) {
            bf16x8 bfrG = *(const bf16x8*)(WpG2 + fbase + (kt << 9));
            accL = __builtin_amdgcn_mfma_f32_16x16x32_bf16(afrA[kt], bfrG, accL, 0, 0, 0);
        }
        const float bb = bg2S[colg];
        const float l0 = fminf(30.f, fmaxf(-30.f, accL[0] + bb));
        const float l1 = fminf(30.f, fmaxf(-30.f, accL[1] + bb));
        const float l2 = fminf(30.f, fmaxf(-30.f, accL[2] + bb));
        const float l3 = fminf(30.f, fmaxf(-30.f, accL[3] + bb));
        const float gl = fminf(30.f, fmaxf(-30.f, agS[colg]));
        float mx = fmaxf(fmaxf(l0, l1), fmaxf(l2, l3));
        mx = fmaxf(mx, __shfl_xor(mx, 16));
        mx = fmaxf(mx, __shfl_xor(mx, 32));
        mx = fmaxf(mx, gl);
        const float e0 = expf(l0 - mx), e1 = expf(l1 - mx);
        const float e2 = expf(l2 - mx), e3 = expf(l3 - mx);
        float s = (e0 + e1) + (e2 + e3);
        s += __shfl_xor(s, 16);
        s += __shfl_xor(s, 32);
        const float eg  = expf(gl - mx);
        const float inv = 1.0f / (s + eg);
        const int rr = rw + (q4 << 2);
        float o = e0 * bf2f(bufVP[swz(rr + 0, colg)])
                + e1 * bf2f(bufVP[swz(rr + 1, colg)])
                + e2 * bf2f(bufVP[swz(rr + 2, colg)])
                + e3 * bf2f(bufVP[swz(rr + 3, colg)]);
        o += __shfl_xor(o, 16);
        o += __shfl_xor(o, 32);
        o = (o + eg * vgS[colg]) * inv;
        if (lane < 16) {
            if (BF16) ((u16*)out)[outq + colg] = f2bf(o);
            else      ((float*)out)[outq + colg] = o;
        }
    }
}

// ---------------------------------------------------------------------------
extern "C" void kernel_launch(void* const* d_in, const int* in_sizes, int n_in,
                              void* d_out, int out_size, void* d_ws, size_t ws_size,
                              hipStream_t stream)
{
    const void* xyz_q  = d_in[0];
    const void* lat    = d_in[1];
    const void* xyz    = d_in[2];
    const void* points = d_in[3];
    const void* Wd1 = d_in[4];
    const void* bd1 = d_in[5];
    const void* Wd2 = d_in[6];
    const void* bd2 = d_in[7];
    const void* Wg1 = d_in[8];
    const void* bg1 = d_in[9];
    const void* Wg2 = d_in[10];
    const void* bg2 = d_in[11];
    const void* Wkg = d_in[12];
    const void* Wvg = d_in[13];
    const void* Wq  = d_in[14];
    const void* Wk  = d_in[15];
    const void* Wv  = d_in[16];

    probe_kernel<<<1, 64, 0, stream>>>((const u32*)lat);

    repack_kernel<1><<<dim3(32, 5), 256, 0, stream>>>(Wd2, Wk, Wv, Wg1, Wg2);
    repack_kernel<0><<<dim3(32, 5), 256, 0, stream>>>(Wd2, Wk, Wv, Wg1, Wg2);
    knn_kernel<1><<<4096, 256, 0, stream>>>(xyz_q, xyz);
    knn_kernel<0><<<4096, 256, 0, stream>>>(xyz_q, xyz);
    gtok_kernel<1><<<4, 256, 0, stream>>>(lat, Wq, Wkg, Wvg, Wg1, bg1, Wg2, bg2);
    gtok_kernel<0><<<4, 256, 0, stream>>>(lat, Wq, Wkg, Wvg, Wg1, bg1, Wg2, bg2);
    attn_kernel<1><<<4096, 256, 0, stream>>>(xyz_q, xyz, points,
                                             Wd1, bd1, bd2, bg1, bg2, d_out);
    attn_kernel<0><<<4096, 256, 0, stream>>>(xyz_q, xyz, points,
                                             Wd1, bd1, bd2, bg1, bg2, d_out);
}